// Round 4
// baseline (156.879 us; speedup 1.0000x reference)
//
#include <hip/hip_runtime.h>
#include <hip/hip_fp16.h>
#include <stdint.h>
#include <math.h>

#define B 4096
#define D 512
#define NIMG_SHIFT 3

#define BM 128
#define BN 128
#define BK 32              // f16 elems per K-step (64 bytes)
#define NKS (D / BK)       // 16
#define NCH (B / BN)       // 32 col chunks

typedef _Float16 f16x8 __attribute__((ext_vector_type(8)));
typedef float f32x4 __attribute__((ext_vector_type(4)));

#define LDSPTR(p) ((__attribute__((address_space(3))) void*)(p))
#define GLPTR(p)  ((const __attribute__((address_space(1))) void*)(p))

// -------- static device workspace (fully rewritten every call) ----
__device__ __half   Q2d[(size_t)B * 1024];   // [r][0:512]=hi*2048, [512:1024]=lo
__device__ __half   G2d[(size_t)B * 1024];
__device__ float    nqd[B], ngd[B], psd[B], spd[B];
__device__ uint32_t bKeyd[B * NCH];
__device__ float    bDnd[B * NCH];
__device__ float    mDnd[B * NCH];
__device__ float    partd[B / 8];

// ---------------- threefry2x32 ----------------
__host__ __device__ inline void tf2x32(uint32_t k0, uint32_t k1,
                                       uint32_t x0, uint32_t x1,
                                       uint32_t& y0, uint32_t& y1) {
  const uint32_t ks2 = k0 ^ k1 ^ 0x1BD11BDAu;
  uint32_t v0 = x0 + k0, v1 = x1 + k1;
#define RR(r) { v0 += v1; v1 = (v1 << (r)) | (v1 >> (32 - (r))); v1 ^= v0; }
  RR(13) RR(15) RR(26) RR(6)   v0 += k1;  v1 += ks2 + 1u;
  RR(17) RR(29) RR(16) RR(24)  v0 += ks2; v1 += k0 + 2u;
  RR(13) RR(15) RR(26) RR(6)   v0 += k0;  v1 += k1 + 3u;
  RR(17) RR(29) RR(16) RR(24)  v0 += k1;  v1 += ks2 + 4u;
  RR(13) RR(15) RR(26) RR(6)   v0 += ks2; v1 += k0 + 5u;
#undef RR
  y0 = v0; y1 = v1;
}

__device__ inline uint32_t draw_bits(uint32_t key0, uint32_t key1, uint32_t flat) {
  uint32_t y0, y1;
  tf2x32(key0, key1, 0u, flat, y0, y1);
  return y1;
}

__device__ inline float gumbel_from_bits(uint32_t bits) {
  float f = __uint_as_float((bits >> 9) | 0x3f800000u) - 1.0f;
  float u = (f == 0.0f) ? 1.17549435e-38f : f;
  return -logf(-logf(u));
}

// ------- Kernel 0: fused fp32 -> f16 hi/lo split (x2048) + row norms -------
__global__ __launch_bounds__(256) void cvtn_k(const float* __restrict__ Q,
                                              const float* __restrict__ G) {
  int gtid = blockIdx.x * 256 + threadIdx.x;
  int wave = gtid >> 6;
  int lane = gtid & 63;
  if (wave >= 2 * B) return;
  const int isG = wave >= B;
  const float* src = isG ? G : Q;
  __half* dst = isG ? G2d : Q2d;
  const int row = isG ? wave - B : wave;
  const float4* p = (const float4*)(src + (size_t)row * D);
  float ssq = 0.0f;
#pragma unroll
  for (int i = 0; i < 2; i++) {
    const int e = lane + 64 * i;       // float4 index within row, 0..127
    float4 v = p[e];
    const float* pv = (const float*)&v;
    __half hh[4] __attribute__((aligned(8)));
    __half ll[4] __attribute__((aligned(8)));
#pragma unroll
    for (int j = 0; j < 4; j++) {
      const float x = pv[j];
      ssq += x * x;
      const float xs = x * 2048.0f;
      const __half h = __float2half(xs);
      hh[j] = h;
      ll[j] = __float2half(xs - __half2float(h));
    }
    *(uint2*)(dst + (size_t)row * 1024 + e * 4) = *(const uint2*)hh;
    *(uint2*)(dst + (size_t)row * 1024 + 512 + e * 4) = *(const uint2*)ll;
  }
#pragma unroll
  for (int off = 32; off; off >>= 1) ssq += __shfl_xor(ssq, off, 64);
  if (lane == 0) { if (isG) ngd[row] = ssq; else nqd[row] = ssq; }
}

// ---------------- Kernel 2: positive categorical sampling ----------------
__global__ __launch_bounds__(256) void pos_k(const float* __restrict__ Q,
                                             const float* __restrict__ G,
                                             uint32_t kp0, uint32_t kp1) {
  __shared__ float Qs[8][D];
  __shared__ float Gs[8][D];
  __shared__ float dots[8][8];
  int t = threadIdx.x;
  int rbase = blockIdx.x * 8;
#pragma unroll
  for (int s = 0; s < 4; s++) {
    int idx = t + 256 * s;
    int rr = idx >> 7;
    int kk = idx & 127;
    ((float4*)&Qs[rr][0])[kk] = ((const float4*)(Q + (size_t)(rbase + rr) * D))[kk];
    ((float4*)&Gs[rr][0])[kk] = ((const float4*)(G + (size_t)(rbase + rr) * D))[kk];
  }
  __syncthreads();
  {
    int p = t >> 2;
    int part = t & 3;
    int i = p >> 3, j = p & 7;
    float s = 0.0f;
    int k0 = part * 128;
    for (int k = k0; k < k0 + 128; k++) s += Qs[i][k] * Gs[j][k];
    s += __shfl_xor(s, 1, 64);
    s += __shfl_xor(s, 2, 64);
    if (part == 0) dots[i][j] = s;
  }
  __syncthreads();
  if (t < 8) {
    int i = t;
    int r = rbase + i;
    float nqr = nqd[r];
    float best = -INFINITY;
    float bdp = 0.0f;
#pragma unroll
    for (int j = 0; j < 8; j++) {
      if (j == i) continue;
      int c = rbase + j;
      float dp = fmaxf(nqr + ngd[c] - 2.0f * dots[i][j], 1e-8f);
      uint32_t bits = draw_bits(kp0, kp1, (uint32_t)(r * B + c));
      float logit = logf(dp) + gumbel_from_bits(bits);
      if (logit > best) { best = logit; bdp = dp; }
    }
    psd[r] = bdp;
    spd[r] = sqrtf(bdp);
  }
}

// ---------------- Kernel 3: MFMA f16-split GEMM + neg-row reductions --------
// BK=32: four 8KB tiles (Ah@0, Al@8K, Bh@16K, Bl@24K) -> 32KB LDS -> ~4 blocks/CU
__global__ __launch_bounds__(256) void neg_k(uint32_t kn0, uint32_t kn1) {
  __shared__ char lds[32768] __attribute__((aligned(16)));
  const int t = threadIdx.x;
  const int l = t & 63;
  const int w = t >> 6;
  const int wr = w >> 1, wc = w & 1;
  const int lane16 = l & 15, g16 = l >> 4;
  const int r0 = blockIdx.y * BM;
  const int c0 = blockIdx.x * BN;

  f32x4 acc[4][4];
#pragma unroll
  for (int mi = 0; mi < 4; mi++)
#pragma unroll
    for (int nj = 0; nj < 4; nj++) acc[mi][nj] = (f32x4){0.f, 0.f, 0.f, 0.f};

  const char* qbase = (const char*)Q2d + (size_t)r0 * 2048;
  const char* gbase = (const char*)G2d + (size_t)c0 * 2048;

  // read-side swizzled fragment offsets (row stride 64B; XOR slot bits[5:4]
  // with row bits[2:1]; bits>=6 untouched -> involution)
  int offA[4], offB[4];
#pragma unroll
  for (int i = 0; i < 4; i++) {
    const int ra = (wr * 64 + i * 16 + lane16);
    const int aa = ra * 64 + g16 * 16;
    offA[i] = aa ^ ((((aa >> 7) & 3)) << 4);
    const int rb = (wc * 64 + i * 16 + lane16);
    const int ab = rb * 64 + g16 * 16;
    offB[i] = ab ^ ((((ab >> 7) & 3)) << 4);
  }

#pragma unroll 1
  for (int ks = 0; ks < NKS; ks++) {
    __syncthreads();
    // stage 4 tiles of [128 rows][64B] via global_load_lds, pre-swizzled source
#pragma unroll
    for (int s = 0; s < 2; s++) {
      const int li = (t + 256 * s) << 4;                // linear dest byte in 8KB tile
      const int aa = li ^ (((li >> 7) & 3) << 4);       // logical (row,col)
      const int row = aa >> 6, col = aa & 63;
      const char* qrow = qbase + (size_t)row * 2048 + ks * 64 + col;
      const char* grow = gbase + (size_t)row * 2048 + ks * 64 + col;
      __builtin_amdgcn_global_load_lds(GLPTR(qrow),        LDSPTR(lds + li),         16, 0, 0);
      __builtin_amdgcn_global_load_lds(GLPTR(qrow + 1024), LDSPTR(lds + 8192 + li),  16, 0, 0);
      __builtin_amdgcn_global_load_lds(GLPTR(grow),        LDSPTR(lds + 16384 + li), 16, 0, 0);
      __builtin_amdgcn_global_load_lds(GLPTR(grow + 1024), LDSPTR(lds + 24576 + li), 16, 0, 0);
    }
    __syncthreads();

    f16x8 ah[4], al[4];
#pragma unroll
    for (int mi = 0; mi < 4; mi++) {
      ah[mi] = *(const f16x8*)(lds + offA[mi]);
      al[mi] = *(const f16x8*)(lds + 8192 + offA[mi]);
    }
#pragma unroll
    for (int nj = 0; nj < 4; nj++) {
      const f16x8 bh = *(const f16x8*)(lds + 16384 + offB[nj]);
      const f16x8 bl = *(const f16x8*)(lds + 24576 + offB[nj]);
#pragma unroll
      for (int mi = 0; mi < 4; mi++) {
        acc[mi][nj] = __builtin_amdgcn_mfma_f32_16x16x32_f16(ah[mi], bh, acc[mi][nj], 0, 0, 0);
        acc[mi][nj] = __builtin_amdgcn_mfma_f32_16x16x32_f16(al[mi], bh, acc[mi][nj], 0, 0, 0);
        acc[mi][nj] = __builtin_amdgcn_mfma_f32_16x16x32_f16(ah[mi], bl, acc[mi][nj], 0, 0, 0);
      }
    }
  }
  __syncthreads();

  // epilogue partial arrays overlaid on LDS
  uint32_t* pKey = (uint32_t*)lds;
  uint32_t* pC   = pKey + 256;
  float*    pD   = (float*)(pC + 256);
  float*    pM   = pD + 256;
  uint32_t* pMC  = (uint32_t*)(pM + 256);

  // distance + per-row reductions. acc holds r*2^22; -2r = -acc * 2^-21
#pragma unroll
  for (int mi = 0; mi < 4; mi++) {
#pragma unroll
    for (int q = 0; q < 4; q++) {
      const int rr = wr * 64 + mi * 16 + g16 * 4 + q;
      const int r = r0 + rr;
      const float nqv = nqd[r];
      const float thr = psd[r] + 1e-4f;
      const int rg = r >> NIMG_SHIFT;
      uint32_t bKey = 0u, bC = 0xFFFFFFFFu, mC = 0xFFFFFFFFu;
      float bD = 0.0f, mD = INFINITY;
#pragma unroll
      for (int nj = 0; nj < 4; nj++) {
        const int c = c0 + wc * 64 + nj * 16 + lane16;
        const float dv = fmaxf(nqv + ngd[c] - acc[mi][nj][q] * 4.76837158203125e-07f, 1e-8f);
        const float dn = ((c >> NIMG_SHIFT) == rg) ? 1e25f : dv;
        if (dn < mD || (dn == mD && (uint32_t)c < mC)) { mD = dn; mC = (uint32_t)c; }
        if (dn < thr) {
          const uint32_t bits = draw_bits(kn0, kn1, (uint32_t)(r * B + c));
          const uint32_t key = (bits >> 9) + 1u;
          if (key > bKey || (key == bKey && (uint32_t)c < bC)) { bKey = key; bC = (uint32_t)c; bD = dn; }
        }
      }
#pragma unroll
      for (int off = 8; off >= 1; off >>= 1) {
        const uint32_t kO = __shfl_xor(bKey, off, 64);
        const uint32_t cO = __shfl_xor(bC, off, 64);
        const float dO = __shfl_xor(bD, off, 64);
        if (kO > bKey || (kO == bKey && cO < bC)) { bKey = kO; bC = cO; bD = dO; }
        const float mdO = __shfl_xor(mD, off, 64);
        const uint32_t mcO = __shfl_xor(mC, off, 64);
        if (mdO < mD || (mdO == mD && mcO < mC)) { mD = mdO; mC = mcO; }
      }
      if (lane16 == 0) {
        const int idx = wc * 128 + rr;
        pKey[idx] = bKey; pC[idx] = bC; pD[idx] = bD; pM[idx] = mD; pMC[idx] = mC;
      }
    }
  }
  __syncthreads();
  if (t < 128) {
    const int i0 = t, i1 = t + 128;
    const uint32_t k0 = pKey[i0], k1 = pKey[i1];
    const uint32_t c0v = pC[i0], c1v = pC[i1];
    const float d0 = pD[i0], d1 = pD[i1];
    uint32_t bk; float bd;
    if (k1 > k0 || (k1 == k0 && k1 != 0u && c1v < c0v)) { bk = k1; bd = d1; }
    else { bk = k0; bd = d0; }
    const float m0 = pM[i0], m1 = pM[i1];
    const uint32_t mc0 = pMC[i0], mc1 = pMC[i1];
    const float md = (m1 < m0 || (m1 == m0 && mc1 < mc0)) ? m1 : m0;
    const int p = (r0 + t) * NCH + blockIdx.x;
    bKeyd[p] = bk; bDnd[p] = bd; mDnd[p] = md;
  }
}

// ---------------- Kernel 4a: per-row chunk combine + softplus, block partial --
__global__ __launch_bounds__(256) void fin1_k() {
  __shared__ float red[8];
  const int t = threadIdx.x;
  const int lrow = t >> 5;              // 0..7 rows per block
  const int ch = t & 31;                // chunk index
  const int r = blockIdx.x * 8 + lrow;
  const int p = r * NCH + ch;
  uint32_t bk = bKeyd[p];
  uint32_t bch = (uint32_t)ch;
  float bd = bDnd[p];
  float md = mDnd[p];
  uint32_t mch = (uint32_t)ch;
#pragma unroll
  for (int off = 16; off >= 1; off >>= 1) {
    const uint32_t kO = __shfl_xor(bk, off, 64);
    const uint32_t cO = __shfl_xor(bch, off, 64);
    const float dO = __shfl_xor(bd, off, 64);
    if (kO > bk || (kO == bk && cO < bch)) { bk = kO; bch = cO; bd = dO; }
    const float mO = __shfl_xor(md, off, 64);
    const uint32_t mcO = __shfl_xor(mch, off, 64);
    if (mO < md || (mO == md && mcO < mch)) { md = mO; mch = mcO; }
  }
  if (ch == 0) {
    const float dn = (bk != 0u) ? bd : md;
    const float x = 1e-4f + spd[r] - sqrtf(dn);
    red[lrow] = fmaxf(x, 0.0f) + log1pf(expf(-fabsf(x)));
  }
  __syncthreads();
  if (t == 0) {
    float s = 0.0f;
#pragma unroll
    for (int i = 0; i < 8; i++) s += red[i];
    partd[blockIdx.x] = s;
  }
}

// ---------------- Kernel 4b: sum 512 partials, mean ----------------
__global__ __launch_bounds__(256) void fin2_k(float* __restrict__ out) {
  __shared__ float red[256];
  const int t = threadIdx.x;
  red[t] = partd[t] + partd[t + 256];
  __syncthreads();
#pragma unroll
  for (int s = 128; s; s >>= 1) {
    if (t < s) red[t] += red[t + s];
    __syncthreads();
  }
  if (t == 0) out[0] = red[0] * (1.0f / (float)B);
}

extern "C" void kernel_launch(void* const* d_in, const int* in_sizes, int n_in,
                              void* d_out, int out_size, void* d_ws, size_t ws_size,
                              hipStream_t stream) {
  (void)in_sizes; (void)n_in; (void)out_size; (void)d_ws; (void)ws_size;
  const float* Q = (const float*)d_in[0];
  const float* G = (const float*)d_in[1];
  float* out = (float*)d_out;

  uint32_t kp0, kp1, kn0, kn1;
  tf2x32(0u, 42u, 0u, 0u, kp0, kp1);
  tf2x32(0u, 42u, 0u, 1u, kn0, kn1);

  hipLaunchKernelGGL(cvtn_k, dim3(2 * B / 4), dim3(256), 0, stream, Q, G);
  hipLaunchKernelGGL(pos_k, dim3(B / 8), dim3(256), 0, stream, Q, G, kp0, kp1);
  hipLaunchKernelGGL(neg_k, dim3(NCH, B / BM), dim3(256), 0, stream, kn0, kn1);
  hipLaunchKernelGGL(fin1_k, dim3(B / 8), dim3(256), 0, stream);
  hipLaunchKernelGGL(fin2_k, dim3(1), dim3(256), 0, stream, out);
}

// Round 5
// 152.354 us; speedup vs baseline: 1.0297x; 1.0297x over previous
//
#include <hip/hip_runtime.h>
#include <hip/hip_fp16.h>
#include <stdint.h>
#include <math.h>

#define B 4096
#define D 512
#define NIMG_SHIFT 3

#define BM 128
#define BN 128
#define BK 32              // f16 elems per K-step (64 bytes)
#define NKS (D / BK)       // 16
#define NCH (B / BN)       // 32 col chunks

typedef _Float16 f16x8 __attribute__((ext_vector_type(8)));
typedef float f32x4 __attribute__((ext_vector_type(4)));

#define LDSPTR(p) ((__attribute__((address_space(3))) void*)(p))
#define GLPTR(p)  ((const __attribute__((address_space(1))) void*)(p))

// -------- static device workspace (fully rewritten every call) ----
__device__ __half   Q2d[(size_t)B * 1024];   // [r][0:512]=hi*2048, [512:1024]=lo
__device__ __half   G2d[(size_t)B * 1024];
__device__ float    nqd[B], ngd[B], psd[B], spd[B];
__device__ uint32_t bKeyd[B * NCH];
__device__ float    bDnd[B * NCH];
__device__ float    mDnd[B * NCH];
__device__ float    partd[B / 8];

// ---------------- threefry2x32 ----------------
__host__ __device__ inline void tf2x32(uint32_t k0, uint32_t k1,
                                       uint32_t x0, uint32_t x1,
                                       uint32_t& y0, uint32_t& y1) {
  const uint32_t ks2 = k0 ^ k1 ^ 0x1BD11BDAu;
  uint32_t v0 = x0 + k0, v1 = x1 + k1;
#define RR(r) { v0 += v1; v1 = (v1 << (r)) | (v1 >> (32 - (r))); v1 ^= v0; }
  RR(13) RR(15) RR(26) RR(6)   v0 += k1;  v1 += ks2 + 1u;
  RR(17) RR(29) RR(16) RR(24)  v0 += ks2; v1 += k0 + 2u;
  RR(13) RR(15) RR(26) RR(6)   v0 += k0;  v1 += k1 + 3u;
  RR(17) RR(29) RR(16) RR(24)  v0 += k1;  v1 += ks2 + 4u;
  RR(13) RR(15) RR(26) RR(6)   v0 += ks2; v1 += k0 + 5u;
#undef RR
  y0 = v0; y1 = v1;
}

__device__ inline uint32_t draw_bits(uint32_t key0, uint32_t key1, uint32_t flat) {
  uint32_t y0, y1;
  tf2x32(key0, key1, 0u, flat, y0, y1);
  return y1;
}

__device__ inline float gumbel_from_bits(uint32_t bits) {
  float f = __uint_as_float((bits >> 9) | 0x3f800000u) - 1.0f;
  float u = (f == 0.0f) ? 1.17549435e-38f : f;
  return -logf(-logf(u));
}

// ------- Kernel 0: fused fp32 -> f16 hi/lo split (x2048) + row norms -------
__global__ __launch_bounds__(256) void cvtn_k(const float* __restrict__ Q,
                                              const float* __restrict__ G) {
  int gtid = blockIdx.x * 256 + threadIdx.x;
  int wave = gtid >> 6;
  int lane = gtid & 63;
  if (wave >= 2 * B) return;
  const int isG = wave >= B;
  const float* src = isG ? G : Q;
  __half* dst = isG ? G2d : Q2d;
  const int row = isG ? wave - B : wave;
  const float4* p = (const float4*)(src + (size_t)row * D);
  float ssq = 0.0f;
#pragma unroll
  for (int i = 0; i < 2; i++) {
    const int e = lane + 64 * i;       // float4 index within row, 0..127
    float4 v = p[e];
    const float* pv = (const float*)&v;
    __half hh[4] __attribute__((aligned(8)));
    __half ll[4] __attribute__((aligned(8)));
#pragma unroll
    for (int j = 0; j < 4; j++) {
      const float x = pv[j];
      ssq += x * x;
      const float xs = x * 2048.0f;
      const __half h = __float2half(xs);
      hh[j] = h;
      ll[j] = __float2half(xs - __half2float(h));
    }
    *(uint2*)(dst + (size_t)row * 1024 + e * 4) = *(const uint2*)hh;
    *(uint2*)(dst + (size_t)row * 1024 + 512 + e * 4) = *(const uint2*)ll;
  }
#pragma unroll
  for (int off = 32; off; off >>= 1) ssq += __shfl_xor(ssq, off, 64);
  if (lane == 0) { if (isG) ngd[row] = ssq; else nqd[row] = ssq; }
}

// ---------------- Kernel 2: positive categorical sampling ----------------
__global__ __launch_bounds__(256) void pos_k(const float* __restrict__ Q,
                                             const float* __restrict__ G,
                                             uint32_t kp0, uint32_t kp1) {
  __shared__ float Qs[8][D];
  __shared__ float Gs[8][D];
  __shared__ float dots[8][8];
  int t = threadIdx.x;
  int rbase = blockIdx.x * 8;
#pragma unroll
  for (int s = 0; s < 4; s++) {
    int idx = t + 256 * s;
    int rr = idx >> 7;
    int kk = idx & 127;
    ((float4*)&Qs[rr][0])[kk] = ((const float4*)(Q + (size_t)(rbase + rr) * D))[kk];
    ((float4*)&Gs[rr][0])[kk] = ((const float4*)(G + (size_t)(rbase + rr) * D))[kk];
  }
  __syncthreads();
  {
    int p = t >> 2;
    int part = t & 3;
    int i = p >> 3, j = p & 7;
    float s = 0.0f;
    int k0 = part * 128;
    for (int k = k0; k < k0 + 128; k++) s += Qs[i][k] * Gs[j][k];
    s += __shfl_xor(s, 1, 64);
    s += __shfl_xor(s, 2, 64);
    if (part == 0) dots[i][j] = s;
  }
  __syncthreads();
  if (t < 8) {
    int i = t;
    int r = rbase + i;
    float nqr = nqd[r];
    float best = -INFINITY;
    float bdp = 0.0f;
#pragma unroll
    for (int j = 0; j < 8; j++) {
      if (j == i) continue;
      int c = rbase + j;
      float dp = fmaxf(nqr + ngd[c] - 2.0f * dots[i][j], 1e-8f);
      uint32_t bits = draw_bits(kp0, kp1, (uint32_t)(r * B + c));
      float logit = logf(dp) + gumbel_from_bits(bits);
      if (logit > best) { best = logit; bdp = dp; }
    }
    psd[r] = bdp;
    spd[r] = sqrtf(bdp);
  }
}

// ---------------- Kernel 3: MFMA f16-split GEMM + neg-row reductions --------
// 2-phase double-buffer (T3-minimum): two 32KB buffers, stage next tile BEFORE
// computing current, single barrier (with compiler vmcnt(0) drain) per K-step.
__global__ __launch_bounds__(256) void neg_k(uint32_t kn0, uint32_t kn1) {
  __shared__ char lds[65536] __attribute__((aligned(16)));
  const int t = threadIdx.x;
  const int l = t & 63;
  const int w = t >> 6;
  const int wr = w >> 1, wc = w & 1;
  const int lane16 = l & 15, g16 = l >> 4;
  const int r0 = blockIdx.y * BM;
  const int c0 = blockIdx.x * BN;

  f32x4 acc[4][4];
#pragma unroll
  for (int mi = 0; mi < 4; mi++)
#pragma unroll
    for (int nj = 0; nj < 4; nj++) acc[mi][nj] = (f32x4){0.f, 0.f, 0.f, 0.f};

  const char* qbase = (const char*)Q2d + (size_t)r0 * 2048;
  const char* gbase = (const char*)G2d + (size_t)c0 * 2048;

  // staging: per-thread linear LDS dest (per 8KB plane) + pre-swizzled source
  const int li0 = t << 4;
  const int li1 = (t + 256) << 4;
  const int aa0 = li0 ^ (((li0 >> 7) & 3) << 4);
  const int aa1 = li1 ^ (((li1 >> 7) & 3) << 4);
  const char* pq0 = qbase + (size_t)(aa0 >> 6) * 2048 + (aa0 & 63);
  const char* pq1 = qbase + (size_t)(aa1 >> 6) * 2048 + (aa1 & 63);
  const char* pg0 = gbase + (size_t)(aa0 >> 6) * 2048 + (aa0 & 63);
  const char* pg1 = gbase + (size_t)(aa1 >> 6) * 2048 + (aa1 & 63);

#define STAGE(CUR) do {                                                                      \
    char* ldst = lds + (CUR) * 32768;                                                        \
    __builtin_amdgcn_global_load_lds(GLPTR(pq0),        LDSPTR(ldst + li0),         16,0,0); \
    __builtin_amdgcn_global_load_lds(GLPTR(pq0 + 1024), LDSPTR(ldst + 8192 + li0),  16,0,0); \
    __builtin_amdgcn_global_load_lds(GLPTR(pg0),        LDSPTR(ldst + 16384 + li0), 16,0,0); \
    __builtin_amdgcn_global_load_lds(GLPTR(pg0 + 1024), LDSPTR(ldst + 24576 + li0), 16,0,0); \
    __builtin_amdgcn_global_load_lds(GLPTR(pq1),        LDSPTR(ldst + li1),         16,0,0); \
    __builtin_amdgcn_global_load_lds(GLPTR(pq1 + 1024), LDSPTR(ldst + 8192 + li1),  16,0,0); \
    __builtin_amdgcn_global_load_lds(GLPTR(pg1),        LDSPTR(ldst + 16384 + li1), 16,0,0); \
    __builtin_amdgcn_global_load_lds(GLPTR(pg1 + 1024), LDSPTR(ldst + 24576 + li1), 16,0,0); \
    pq0 += 64; pq1 += 64; pg0 += 64; pg1 += 64;                                              \
  } while (0)

  // read-side swizzled fragment offsets (row stride 64B; XOR slot bits[5:4]
  // with row bits[2:1]; involution, matches STAGE's source pre-swizzle)
  int offA[4], offB[4];
#pragma unroll
  for (int i = 0; i < 4; i++) {
    const int ra = (wr * 64 + i * 16 + lane16);
    const int aa = ra * 64 + g16 * 16;
    offA[i] = aa ^ ((((aa >> 7) & 3)) << 4);
    const int rb = (wc * 64 + i * 16 + lane16);
    const int ab = rb * 64 + g16 * 16;
    offB[i] = ab ^ ((((ab >> 7) & 3)) << 4);
  }

#define COMPUTE(CUR) do {                                                                    \
    const char* lsrc = lds + (CUR) * 32768;                                                  \
    f16x8 ah[4], al[4];                                                                      \
    _Pragma("unroll")                                                                        \
    for (int mi = 0; mi < 4; mi++) {                                                         \
      ah[mi] = *(const f16x8*)(lsrc + offA[mi]);                                             \
      al[mi] = *(const f16x8*)(lsrc + 8192 + offA[mi]);                                      \
    }                                                                                        \
    _Pragma("unroll")                                                                        \
    for (int nj = 0; nj < 4; nj++) {                                                         \
      const f16x8 bh = *(const f16x8*)(lsrc + 16384 + offB[nj]);                             \
      const f16x8 bl = *(const f16x8*)(lsrc + 24576 + offB[nj]);                             \
      _Pragma("unroll")                                                                      \
      for (int mi = 0; mi < 4; mi++) {                                                       \
        acc[mi][nj] = __builtin_amdgcn_mfma_f32_16x16x32_f16(ah[mi], bh, acc[mi][nj],0,0,0); \
        acc[mi][nj] = __builtin_amdgcn_mfma_f32_16x16x32_f16(al[mi], bh, acc[mi][nj],0,0,0); \
        acc[mi][nj] = __builtin_amdgcn_mfma_f32_16x16x32_f16(ah[mi], bl, acc[mi][nj],0,0,0); \
      }                                                                                      \
    }                                                                                        \
  } while (0)

  STAGE(0);
  __syncthreads();
#pragma unroll 1
  for (int it = 0; it < NKS / 2 - 1; it++) {
    STAGE(1);
    COMPUTE(0);
    __syncthreads();
    STAGE(0);
    COMPUTE(1);
    __syncthreads();
  }
  STAGE(1);
  COMPUTE(0);
  __syncthreads();
  COMPUTE(1);
  __syncthreads();

#undef STAGE
#undef COMPUTE

  // epilogue partial arrays overlaid on LDS (buffer 0; all compute done)
  uint32_t* pKey = (uint32_t*)lds;
  uint32_t* pC   = pKey + 256;
  float*    pD   = (float*)(pC + 256);
  float*    pM   = pD + 256;
  uint32_t* pMC  = (uint32_t*)(pM + 256);

  // distance + per-row reductions. acc holds r*2^22; -2r = -acc * 2^-21
#pragma unroll
  for (int mi = 0; mi < 4; mi++) {
#pragma unroll
    for (int q = 0; q < 4; q++) {
      const int rr = wr * 64 + mi * 16 + g16 * 4 + q;
      const int r = r0 + rr;
      const float nqv = nqd[r];
      const float thr = psd[r] + 1e-4f;
      const int rg = r >> NIMG_SHIFT;
      uint32_t bKey = 0u, bC = 0xFFFFFFFFu, mC = 0xFFFFFFFFu;
      float bD = 0.0f, mD = INFINITY;
#pragma unroll
      for (int nj = 0; nj < 4; nj++) {
        const int c = c0 + wc * 64 + nj * 16 + lane16;
        const float dv = fmaxf(nqv + ngd[c] - acc[mi][nj][q] * 4.76837158203125e-07f, 1e-8f);
        const float dn = ((c >> NIMG_SHIFT) == rg) ? 1e25f : dv;
        if (dn < mD || (dn == mD && (uint32_t)c < mC)) { mD = dn; mC = (uint32_t)c; }
        if (dn < thr) {
          const uint32_t bits = draw_bits(kn0, kn1, (uint32_t)(r * B + c));
          const uint32_t key = (bits >> 9) + 1u;
          if (key > bKey || (key == bKey && (uint32_t)c < bC)) { bKey = key; bC = (uint32_t)c; bD = dn; }
        }
      }
#pragma unroll
      for (int off = 8; off >= 1; off >>= 1) {
        const uint32_t kO = __shfl_xor(bKey, off, 64);
        const uint32_t cO = __shfl_xor(bC, off, 64);
        const float dO = __shfl_xor(bD, off, 64);
        if (kO > bKey || (kO == bKey && cO < bC)) { bKey = kO; bC = cO; bD = dO; }
        const float mdO = __shfl_xor(mD, off, 64);
        const uint32_t mcO = __shfl_xor(mC, off, 64);
        if (mdO < mD || (mdO == mD && mcO < mC)) { mD = mdO; mC = mcO; }
      }
      if (lane16 == 0) {
        const int idx = wc * 128 + rr;
        pKey[idx] = bKey; pC[idx] = bC; pD[idx] = bD; pM[idx] = mD; pMC[idx] = mC;
      }
    }
  }
  __syncthreads();
  if (t < 128) {
    const int i0 = t, i1 = t + 128;
    const uint32_t k0 = pKey[i0], k1 = pKey[i1];
    const uint32_t c0v = pC[i0], c1v = pC[i1];
    const float d0 = pD[i0], d1 = pD[i1];
    uint32_t bk; float bd;
    if (k1 > k0 || (k1 == k0 && k1 != 0u && c1v < c0v)) { bk = k1; bd = d1; }
    else { bk = k0; bd = d0; }
    const float m0 = pM[i0], m1 = pM[i1];
    const uint32_t mc0 = pMC[i0], mc1 = pMC[i1];
    const float md = (m1 < m0 || (m1 == m0 && mc1 < mc0)) ? m1 : m0;
    const int p = (r0 + t) * NCH + blockIdx.x;
    bKeyd[p] = bk; bDnd[p] = bd; mDnd[p] = md;
  }
}

// ---------------- Kernel 4a: per-row chunk combine + softplus, block partial --
__global__ __launch_bounds__(256) void fin1_k() {
  __shared__ float red[8];
  const int t = threadIdx.x;
  const int lrow = t >> 5;              // 0..7 rows per block
  const int ch = t & 31;                // chunk index
  const int r = blockIdx.x * 8 + lrow;
  const int p = r * NCH + ch;
  uint32_t bk = bKeyd[p];
  uint32_t bch = (uint32_t)ch;
  float bd = bDnd[p];
  float md = mDnd[p];
  uint32_t mch = (uint32_t)ch;
#pragma unroll
  for (int off = 16; off >= 1; off >>= 1) {
    const uint32_t kO = __shfl_xor(bk, off, 64);
    const uint32_t cO = __shfl_xor(bch, off, 64);
    const float dO = __shfl_xor(bd, off, 64);
    if (kO > bk || (kO == bk && cO < bch)) { bk = kO; bch = cO; bd = dO; }
    const float mO = __shfl_xor(md, off, 64);
    const uint32_t mcO = __shfl_xor(mch, off, 64);
    if (mO < md || (mO == md && mcO < mch)) { md = mO; mch = mcO; }
  }
  if (ch == 0) {
    const float dn = (bk != 0u) ? bd : md;
    const float x = 1e-4f + spd[r] - sqrtf(dn);
    red[lrow] = fmaxf(x, 0.0f) + log1pf(expf(-fabsf(x)));
  }
  __syncthreads();
  if (t == 0) {
    float s = 0.0f;
#pragma unroll
    for (int i = 0; i < 8; i++) s += red[i];
    partd[blockIdx.x] = s;
  }
}

// ---------------- Kernel 4b: sum 512 partials, mean ----------------
__global__ __launch_bounds__(256) void fin2_k(float* __restrict__ out) {
  __shared__ float red[256];
  const int t = threadIdx.x;
  red[t] = partd[t] + partd[t + 256];
  __syncthreads();
#pragma unroll
  for (int s = 128; s; s >>= 1) {
    if (t < s) red[t] += red[t + s];
    __syncthreads();
  }
  if (t == 0) out[0] = red[0] * (1.0f / (float)B);
}

extern "C" void kernel_launch(void* const* d_in, const int* in_sizes, int n_in,
                              void* d_out, int out_size, void* d_ws, size_t ws_size,
                              hipStream_t stream) {
  (void)in_sizes; (void)n_in; (void)out_size; (void)d_ws; (void)ws_size;
  const float* Q = (const float*)d_in[0];
  const float* G = (const float*)d_in[1];
  float* out = (float*)d_out;

  uint32_t kp0, kp1, kn0, kn1;
  tf2x32(0u, 42u, 0u, 0u, kp0, kp1);
  tf2x32(0u, 42u, 0u, 1u, kn0, kn1);

  hipLaunchKernelGGL(cvtn_k, dim3(2 * B / 4), dim3(256), 0, stream, Q, G);
  hipLaunchKernelGGL(pos_k, dim3(B / 8), dim3(256), 0, stream, Q, G, kp0, kp1);
  hipLaunchKernelGGL(neg_k, dim3(NCH, B / BM), dim3(256), 0, stream, kn0, kn1);
  hipLaunchKernelGGL(fin1_k, dim3(B / 8), dim3(256), 0, stream);
  hipLaunchKernelGGL(fin2_k, dim3(1), dim3(256), 0, stream, out);
}